// Round 1
// baseline (371.760 us; speedup 1.0000x reference)
//
#include <hip/hip_runtime.h>

#define SEQ   16384
#define NB    4
#define NROWS (NB*SEQ)      // 65536
#define NC    128           // chunks
#define CL    128           // chunk length

typedef short bf16x8 __attribute__((ext_vector_type(8)));
typedef float f32x4  __attribute__((ext_vector_type(4)));

__device__ inline float bf2f(ushort u) {
    unsigned int t = ((unsigned int)u) << 16;
    float f; __builtin_memcpy(&f, &t, 4); return f;
}
__device__ inline ushort f2bf(float f) {
    unsigned int b; __builtin_memcpy(&b, &f, 4);
    unsigned int r = (b + 0x7FFFu + ((b >> 16) & 1u)) >> 16;
    return (ushort)r;
}

// ---------------- weight prep: build bf16 transposed weights ----------------
__global__ __launch_bounds__(256) void prep_weights(
    const float* __restrict__ Wf, const float* __restrict__ Wb,
    const float* __restrict__ Wo, const float* __restrict__ Wgf,
    const float* __restrict__ Wgb,
    ushort* __restrict__ WvTf, ushort* __restrict__ WvTb,
    ushort* __restrict__ WoT,  ushort* __restrict__ WgTf,
    ushort* __restrict__ WgTb)
{
    int idx = blockIdx.x * 256 + threadIdx.x;
    if (idx < 65536) {
        int n = idx >> 8, k = idx & 255;
        WvTf[n*256 + k] = f2bf(Wf[k*512 + 256 + n]);
    } else if (idx < 131072) {
        int j = idx - 65536; int n = j >> 8, k = j & 255;
        WvTb[n*256 + k] = f2bf(Wb[k*512 + 256 + n]);
    } else if (idx < 262144) {
        int j = idx - 131072; int n = j >> 9, k = j & 511;
        WoT[n*512 + k] = f2bf(Wo[k*256 + n]);
    } else if (idx < 266240) {
        int j = idx - 262144; int s = j >> 8, k = j & 255;
        WgTf[s*256 + k] = f2bf(Wgf[k*16 + s]);
    } else if (idx < 270336) {
        int j = idx - 266240; int s = j >> 8, k = j & 255;
        WgTb[s*256 + k] = f2bf(Wgb[k*16 + s]);
    }
}

// ---------------- MFMA GEMM: 64x256 tile, N=256 full width ----------------
// A: [M][KTOT] (fp32 or bf16), BT: [256][KTOT] bf16, out: [M][256]
template<int KTOT, bool A_F32, bool OUT_BF16>
__global__ __launch_bounds__(256) void gemm64x256(
    const void* __restrict__ Ap, const ushort* __restrict__ BT,
    const float* __restrict__ bias, void* __restrict__ Outp)
{
    __shared__ ushort Al[64 * 40];
    __shared__ ushort Bl[256 * 40];
    const int tid = threadIdx.x;
    const int m0 = blockIdx.x * 64;
    const int w = tid >> 6, l = tid & 63;
    const int l15 = l & 15, lk = (l >> 4) * 8;
    f32x4 acc[4][4] = {};

    for (int kk = 0; kk < KTOT; kk += 32) {
        if constexpr (A_F32) {
            const float* A = (const float*)Ap;
            #pragma unroll
            for (int i = 0; i < 2; ++i) {
                int idx = tid + i * 256;           // 512 float4 loads
                int r = idx >> 3, c = idx & 7;
                float4 v = *(const float4*)(A + (size_t)(m0 + r) * KTOT + kk + c * 4);
                ushort4 u;
                u.x = f2bf(v.x); u.y = f2bf(v.y); u.z = f2bf(v.z); u.w = f2bf(v.w);
                *(ushort4*)&Al[r * 40 + c * 4] = u;
            }
        } else {
            const ushort* A = (const ushort*)Ap;
            int r = tid >> 2, c = tid & 3;         // 256 uint4 loads
            uint4 v = *(const uint4*)(A + (size_t)(m0 + r) * KTOT + kk + c * 8);
            *(uint4*)&Al[r * 40 + c * 8] = v;
        }
        #pragma unroll
        for (int i = 0; i < 4; ++i) {
            int idx = tid + i * 256;               // 1024 uint4 loads
            int r = idx >> 2, c = idx & 3;
            uint4 v = *(const uint4*)(BT + (size_t)r * KTOT + kk + c * 8);
            *(uint4*)&Bl[r * 40 + c * 8] = v;
        }
        __syncthreads();
        bf16x8 af[4], bfr[4];
        #pragma unroll
        for (int m = 0; m < 4; ++m)
            af[m] = *(const bf16x8*)&Al[(m * 16 + l15) * 40 + lk];
        #pragma unroll
        for (int n = 0; n < 4; ++n)
            bfr[n] = *(const bf16x8*)&Bl[(w * 64 + n * 16 + l15) * 40 + lk];
        #pragma unroll
        for (int m = 0; m < 4; ++m)
            #pragma unroll
            for (int n = 0; n < 4; ++n)
                acc[m][n] = __builtin_amdgcn_mfma_f32_16x16x32_bf16(af[m], bfr[n], acc[m][n], 0, 0, 0);
        __syncthreads();
    }
    const int rbase = (l >> 4) * 4;
    #pragma unroll
    for (int m = 0; m < 4; ++m) {
        #pragma unroll
        for (int n = 0; n < 4; ++n) {
            int col = w * 64 + n * 16 + l15;
            float bv = bias[col];
            #pragma unroll
            for (int r = 0; r < 4; ++r) {
                int row = m0 + m * 16 + rbase + r;
                float vv = acc[m][n][r] + bv;
                if constexpr (OUT_BF16)
                    ((ushort*)Outp)[(size_t)row * 256 + col] = f2bf(vv);
                else
                    ((float*)Outp)[(size_t)row * 256 + col] = vv;
            }
        }
    }
}

// ---------------- gate: gw = sigmoid(value @ Wg + bg), N=16 ----------------
__global__ __launch_bounds__(256) void gate_kernel(
    const ushort* __restrict__ value, const ushort* __restrict__ WgT,
    const float* __restrict__ bg, float* __restrict__ gw)
{
    __shared__ ushort rowbuf[16 * 264];
    const int tid = threadIdx.x;
    const size_t r0 = (size_t)blockIdx.x * 16;
    #pragma unroll
    for (int i = 0; i < 2; ++i) {
        int idx = tid + i * 256;       // 512 uint4 = 16 rows * 32
        int r = idx >> 5, c = idx & 31;
        uint4 v = *(const uint4*)(value + (r0 + r) * 256 + c * 8);
        *(uint4*)&rowbuf[r * 264 + c * 8] = v;
    }
    __syncthreads();
    const int r = tid >> 4, s = tid & 15;
    const ushort* wrow = WgT + s * 256;
    float acc = bg[s];
    for (int k = 0; k < 256; k += 8) {
        uint4 a = *(const uint4*)&rowbuf[r * 264 + k];
        uint4 b = *(const uint4*)(wrow + k);
        unsigned int aa[4] = {a.x, a.y, a.z, a.w};
        unsigned int bb[4] = {b.x, b.y, b.z, b.w};
        #pragma unroll
        for (int i = 0; i < 4; ++i) {
            float alo = bf2f((ushort)(aa[i] & 0xffffu));
            float ahi = bf2f((ushort)(aa[i] >> 16));
            float blo = bf2f((ushort)(bb[i] & 0xffffu));
            float bhi = bf2f((ushort)(bb[i] >> 16));
            acc += alo * blo + ahi * bhi;
        }
    }
    gw[(r0 + r) * 16 + s] = 1.f / (1.f + __expf(-acc));
}

// ---------------- pass A: per-chunk local scan + decay products ----------------
__global__ __launch_bounds__(256) void chunk_local(
    const ushort* __restrict__ value_f, const ushort* __restrict__ value_b,
    const float* __restrict__ gw, float* __restrict__ L, float* __restrict__ P)
{
    const int chunk = blockIdx.x, b = blockIdx.y, dir = blockIdx.z;
    const int d = threadIdx.x;
    __shared__ float gs[CL * 16];
    const float* gwd = gw + ((size_t)(dir * NB + b) * SEQ + (size_t)chunk * CL) * 16;
    for (int i = threadIdx.x; i < CL * 4; i += 256)
        *(float4*)&gs[i * 4] = *(const float4*)(gwd + i * 4);
    __syncthreads();
    const ushort* vptr = (dir ? value_b : value_f) + (size_t)b * SEQ * 256 + d;
    float c[16], p[16];
    #pragma unroll
    for (int s = 0; s < 16; ++s) { c[s] = 0.f; p[s] = 1.f; }
    const int t_base = chunk * CL;
    for (int i = 0; i < CL; ++i) {
        int row = dir ? (CL - 1 - i) : i;
        float g[16];
        #pragma unroll
        for (int q = 0; q < 4; ++q)
            *(float4*)&g[q * 4] = *(const float4*)&gs[row * 16 + q * 4];
        float v = bf2f(vptr[(size_t)(t_base + row) * 256]);
        #pragma unroll
        for (int s = 0; s < 16; ++s) { c[s] = v + g[s] * (c[s] - v); p[s] *= g[s]; }
    }
    float* Lp = L + ((size_t)(dir * NB + b) * NC + chunk) * 4096 + d;
    #pragma unroll
    for (int s = 0; s < 16; ++s) Lp[s * 256] = c[s];
    if (d == 0) {
        float* Pp = P + ((size_t)(dir * NB + b) * NC + chunk) * 16;
        #pragma unroll
        for (int s = 0; s < 16; ++s) Pp[s] = p[s];
    }
}

// ---------------- pass B: chunk-level recurrence (in-place L -> E) ----------------
__global__ __launch_bounds__(256) void chunk_scan(
    float* __restrict__ L, const float* __restrict__ P)
{
    const int bid = blockIdx.x;             // 128 = 2*4*16
    const int dir = bid >> 6, b = (bid >> 4) & 3, s = bid & 15;
    const int d = threadIdx.x;
    const size_t base0 = (size_t)(dir * NB + b) * NC * 4096;
    float e = 0.f;
    for (int i = 0; i < NC; ++i) {
        int k = dir ? (NC - 1 - i) : i;
        size_t off = base0 + (size_t)k * 4096 + s * 256 + d;
        float l = L[off];
        float pv = P[((size_t)(dir * NB + b) * NC + k) * 16 + s];
        L[off] = e;
        e = pv * e + l;
    }
}

// ---------------- pass C: re-run local scan with entry state, emit outputs ----------------
__global__ __launch_bounds__(256) void chunk_out(
    const ushort* __restrict__ value_f, const ushort* __restrict__ value_b,
    const float* __restrict__ gw, const float* __restrict__ L,
    const float* __restrict__ A_f, const float* __restrict__ A_b,
    ushort* __restrict__ combined)
{
    const int chunk = blockIdx.x, b = blockIdx.y, dir = blockIdx.z;
    const int d = threadIdx.x;
    __shared__ float gs[CL * 16];
    const float* gwd = gw + ((size_t)(dir * NB + b) * SEQ + (size_t)chunk * CL) * 16;
    for (int i = threadIdx.x; i < CL * 4; i += 256)
        *(float4*)&gs[i * 4] = *(const float4*)(gwd + i * 4);
    __syncthreads();
    const ushort* vptr = (dir ? value_b : value_f) + (size_t)b * SEQ * 256 + d;
    const float* Ad = dir ? A_b : A_f;
    const float* Lp = L + ((size_t)(dir * NB + b) * NC + chunk) * 4096 + d;
    float a[16], c[16];
    #pragma unroll
    for (int s = 0; s < 16; ++s) { a[s] = Ad[s * 256 + d]; c[s] = Lp[s * 256]; }
    const int t_base = chunk * CL;
    for (int i = 0; i < CL; ++i) {
        int row = dir ? (CL - 1 - i) : i;
        float g[16];
        #pragma unroll
        for (int q = 0; q < 4; ++q)
            *(float4*)&g[q * 4] = *(const float4*)&gs[row * 16 + q * 4];
        int t = t_base + row;
        float v = bf2f(vptr[(size_t)t * 256]);
        float o = 0.f;
        #pragma unroll
        for (int s = 0; s < 16; ++s) {
            c[s] = v + g[s] * (c[s] - v);
            o += a[s] * g[s] * c[s];
        }
        combined[((size_t)b * SEQ + t) * 512 + dir * 256 + d] = f2bf(o);
    }
}

// ---------------- layernorm ----------------
__global__ __launch_bounds__(256) void ln_kernel(
    const float* __restrict__ preLN, const float* __restrict__ g,
    const float* __restrict__ bta, float* __restrict__ out)
{
    const int w = threadIdx.x >> 6, l = threadIdx.x & 63;
    const size_t row = (size_t)blockIdx.x * 4 + w;
    float4 v = *(const float4*)(preLN + row * 256 + l * 4);
    float s1 = v.x + v.y + v.z + v.w;
    float s2 = v.x * v.x + v.y * v.y + v.z * v.z + v.w * v.w;
    #pragma unroll
    for (int m = 1; m < 64; m <<= 1) {
        s1 += __shfl_xor(s1, m, 64);
        s2 += __shfl_xor(s2, m, 64);
    }
    float mu = s1 * (1.f / 256.f);
    float var = s2 * (1.f / 256.f) - mu * mu;
    float rs = rsqrtf(var + 1e-5f);
    float4 gg = *(const float4*)(g + l * 4);
    float4 bb = *(const float4*)(bta + l * 4);
    float4 o;
    o.x = (v.x - mu) * rs * gg.x + bb.x;
    o.y = (v.y - mu) * rs * gg.y + bb.y;
    o.z = (v.z - mu) * rs * gg.z + bb.z;
    o.w = (v.w - mu) * rs * gg.w + bb.w;
    *(float4*)(out + row * 256 + l * 4) = o;
}

extern "C" void kernel_launch(void* const* d_in, const int* in_sizes, int n_in,
                              void* d_out, int out_size, void* d_ws, size_t ws_size,
                              hipStream_t stream)
{
    const float* x       = (const float*)d_in[0];
    const float* W_fproj = (const float*)d_in[1];
    const float* b_fproj = (const float*)d_in[2];
    const float* A_f     = (const float*)d_in[3];
    const float* W_fgate = (const float*)d_in[4];
    const float* b_fgate = (const float*)d_in[5];
    const float* W_bproj = (const float*)d_in[6];
    const float* b_bproj = (const float*)d_in[7];
    const float* A_b     = (const float*)d_in[8];
    const float* W_bgate = (const float*)d_in[9];
    const float* b_bgate = (const float*)d_in[10];
    const float* W_out   = (const float*)d_in[11];
    const float* b_out   = (const float*)d_in[12];
    const float* ln_g    = (const float*)d_in[13];
    const float* ln_b    = (const float*)d_in[14];

    char* ws = (char*)d_ws;
    ushort* value_f  = (ushort*)(ws + 0);             // 33554432 B
    ushort* value_b  = (ushort*)(ws + 33554432);      // 33554432 B
    float*  gw       = (float*) (ws + 67108864);      // 8388608 B  [dir][b][t][16]
    float*  L        = (float*) (ws + 75497472);      // 16777216 B [dir][b][chunk][s][d]
    float*  P        = (float*) (ws + 92274688);      // 524288 B
    ushort* combined = (ushort*)(ws + 92798976);      // 67108864 B [row][512]
    ushort* WvTf     = (ushort*)(ws + 159907840);     // 131072 B
    ushort* WvTb     = (ushort*)(ws + 160038912);     // 131072 B
    ushort* WoT      = (ushort*)(ws + 160169984);     // 262144 B
    ushort* WgTf     = (ushort*)(ws + 160432128);     // 8192 B
    ushort* WgTb     = (ushort*)(ws + 160440320);     // 8192 B
    float*  preLN    = (float*)(ws + 0);              // aliases value_f/value_b (dead by then)

    prep_weights<<<1056, 256, 0, stream>>>(W_fproj, W_bproj, W_out, W_fgate, W_bgate,
                                           WvTf, WvTb, WoT, WgTf, WgTb);
    gemm64x256<256, true, true><<<NROWS / 64, 256, 0, stream>>>(x, WvTf, b_fproj + 256, value_f);
    gemm64x256<256, true, true><<<NROWS / 64, 256, 0, stream>>>(x, WvTb, b_bproj + 256, value_b);
    gate_kernel<<<NROWS / 16, 256, 0, stream>>>(value_f, WgTf, b_fgate, gw);
    gate_kernel<<<NROWS / 16, 256, 0, stream>>>(value_b, WgTb, b_bgate, gw + (size_t)NB * SEQ * 16);
    chunk_local<<<dim3(NC, NB, 2), 256, 0, stream>>>(value_f, value_b, gw, L, P);
    chunk_scan<<<128, 256, 0, stream>>>(L, P);
    chunk_out<<<dim3(NC, NB, 2), 256, 0, stream>>>(value_f, value_b, gw, L, A_f, A_b, combined);
    gemm64x256<512, false, false><<<NROWS / 64, 256, 0, stream>>>(combined, WoT, b_out, preLN);
    ln_kernel<<<NROWS / 4, 256, 0, stream>>>(preLN, ln_g, ln_b, (float*)d_out);
}

// Round 2
// 271.150 us; speedup vs baseline: 1.3710x; 1.3710x over previous
//
#include <hip/hip_runtime.h>

#define SEQ   16384
#define NB    4
#define NROWS 65536
#define NC    256           // chunks per (dir,b)
#define CL    64            // chunk length

typedef short bf16x8 __attribute__((ext_vector_type(8)));
typedef float f32x4  __attribute__((ext_vector_type(4)));

__device__ inline float bf2f(ushort u) {
    unsigned int t = ((unsigned int)u) << 16;
    float f; __builtin_memcpy(&f, &t, 4); return f;
}
__device__ inline ushort f2bf(float f) {
    unsigned int b; __builtin_memcpy(&b, &f, 4);
    unsigned int r = (b + 0x7FFFu + ((b >> 16) & 1u)) >> 16;
    return (ushort)r;
}

// ---------------- weight prep ----------------
// BTv [2][256 n][256 k], WoT [256 n][512 k], WgT [2][16 s][256 k], bias_v [2][256]
__global__ __launch_bounds__(256) void prep_weights(
    const float* __restrict__ Wf, const float* __restrict__ Wb,
    const float* __restrict__ Wo, const float* __restrict__ Wgf,
    const float* __restrict__ Wgb, const float* __restrict__ bfp,
    const float* __restrict__ bbp,
    ushort* __restrict__ BTv, ushort* __restrict__ WoT,
    ushort* __restrict__ WgT, float* __restrict__ bias_v)
{
    int idx = blockIdx.x * 256 + threadIdx.x;
    if (idx < 131072) {                 // BTv
        int dir = idx >> 16, j = idx & 65535, n = j >> 8, k = j & 255;
        const float* W = dir ? Wb : Wf;
        BTv[idx] = f2bf(W[k * 512 + 256 + n]);
    } else if (idx < 262144) {          // WoT
        int j = idx - 131072; int n = j >> 9, k = j & 511;
        WoT[j] = f2bf(Wo[k * 256 + n]);
    } else if (idx < 270336) {          // WgT
        int j = idx - 262144; int dir = j >> 12, jj = j & 4095, s = jj >> 8, k = jj & 255;
        WgT[j] = f2bf((dir ? Wgb : Wgf)[k * 16 + s]);
    } else if (idx < 270848) {          // bias_v
        int j = idx - 270336; int dir = j >> 8, n = j & 255;
        bias_v[j] = (dir ? bbp : bfp)[256 + n];
    }
}

// ---------------- x -> bf16 ----------------
__global__ __launch_bounds__(256) void xcvt(
    const float* __restrict__ x, ushort* __restrict__ xb)
{
    size_t i = ((size_t)blockIdx.x * 256 + threadIdx.x) * 8;
    float4 a = *(const float4*)(x + i);
    float4 b = *(const float4*)(x + i + 4);
    ushort u[8];
    u[0] = f2bf(a.x); u[1] = f2bf(a.y); u[2] = f2bf(a.z); u[3] = f2bf(a.w);
    u[4] = f2bf(b.x); u[5] = f2bf(b.y); u[6] = f2bf(b.z); u[7] = f2bf(b.w);
    *(uint4*)(xb + i) = *(uint4*)u;
}

// ---------------- value GEMM: 64x256 tile, grid.y = dir ----------------
// xb [row][256] bf16, BTv slice [256 n][256 k] -> value [row][512] slice
__global__ __launch_bounds__(256) void gemm_value(
    const ushort* __restrict__ xb, const ushort* __restrict__ BTv,
    const float* __restrict__ bias_v, ushort* __restrict__ value)
{
    __shared__ ushort Al[64 * 40];
    __shared__ ushort Bl[256 * 40];
    const int tid = threadIdx.x;
    const int m0 = blockIdx.x * 64, dir = blockIdx.y;
    const ushort* BT = BTv + dir * 65536;
    const int w = tid >> 6, l = tid & 63, l15 = l & 15, lk = (l >> 4) * 8;
    f32x4 acc[4][4] = {};

    for (int kk = 0; kk < 256; kk += 32) {
        {
            int r = tid >> 2, c = tid & 3;
            *(uint4*)&Al[r * 40 + c * 8] = *(const uint4*)(xb + (size_t)(m0 + r) * 256 + kk + c * 8);
        }
        #pragma unroll
        for (int i = 0; i < 4; ++i) {
            int idx = tid + i * 256; int r = idx >> 2, c = idx & 3;
            *(uint4*)&Bl[r * 40 + c * 8] = *(const uint4*)(BT + (size_t)r * 256 + kk + c * 8);
        }
        __syncthreads();
        bf16x8 af[4], bfr[4];
        #pragma unroll
        for (int m = 0; m < 4; ++m) af[m] = *(const bf16x8*)&Al[(m * 16 + l15) * 40 + lk];
        #pragma unroll
        for (int n = 0; n < 4; ++n) bfr[n] = *(const bf16x8*)&Bl[(w * 64 + n * 16 + l15) * 40 + lk];
        #pragma unroll
        for (int m = 0; m < 4; ++m)
            #pragma unroll
            for (int n = 0; n < 4; ++n)
                acc[m][n] = __builtin_amdgcn_mfma_f32_16x16x32_bf16(af[m], bfr[n], acc[m][n], 0, 0, 0);
        __syncthreads();
    }
    const int rbase = (l >> 4) * 4;
    #pragma unroll
    for (int m = 0; m < 4; ++m)
        #pragma unroll
        for (int n = 0; n < 4; ++n) {
            int col = w * 64 + n * 16 + l15;
            float bv = bias_v[dir * 256 + col];
            #pragma unroll
            for (int r = 0; r < 4; ++r) {
                int row = m0 + m * 16 + rbase + r;
                value[(size_t)row * 512 + dir * 256 + col] = f2bf(acc[m][n][r] + bv);
            }
        }
}

// ---------------- gate via MFMA: 64 rows x 16 s, grid.y = dir ----------------
__global__ __launch_bounds__(256) void gate_mfma(
    const ushort* __restrict__ value, const ushort* __restrict__ WgT,
    const float* __restrict__ bgf, const float* __restrict__ bgb,
    float* __restrict__ gw)
{
    __shared__ ushort Av[64 * 264];
    const int tid = threadIdx.x;
    const int r0 = blockIdx.x * 64, dir = blockIdx.y;
    #pragma unroll
    for (int i = 0; i < 8; ++i) {
        int idx = tid + i * 256; int r = idx >> 5, c = idx & 31;
        *(uint4*)&Av[r * 264 + c * 8] =
            *(const uint4*)(value + (size_t)(r0 + r) * 512 + dir * 256 + c * 8);
    }
    __syncthreads();
    const int w = tid >> 6, l = tid & 63, l15 = l & 15, lk = (l >> 4) * 8;
    const ushort* Wg = WgT + dir * 4096;
    f32x4 acc = {};
    #pragma unroll
    for (int kk = 0; kk < 256; kk += 32) {
        bf16x8 af = *(const bf16x8*)&Av[(w * 16 + l15) * 264 + kk + lk];
        bf16x8 bf = *(const bf16x8*)(Wg + l15 * 256 + kk + lk);
        acc = __builtin_amdgcn_mfma_f32_16x16x32_bf16(af, bf, acc, 0, 0, 0);
    }
    const float* bg = dir ? bgb : bgf;
    float bgs = bg[l15];
    const int rbase = (l >> 4) * 4;
    #pragma unroll
    for (int r = 0; r < 4; ++r) {
        int gr = r0 + w * 16 + rbase + r;
        int b = gr >> 14, t = gr & 16383;
        float sv = 1.f / (1.f + __expf(-(acc[r] + bgs)));
        gw[((size_t)(dir * NB + b) * SEQ + t) * 16 + l15] = sv;
    }
}

// ---------------- pass A: local chunk-final states + decay products ----------------
__global__ __launch_bounds__(128) void pass_a(
    const ushort* __restrict__ value, const float* __restrict__ gw,
    float* __restrict__ L, float* __restrict__ P)
{
    const int chunk = blockIdx.x, b = blockIdx.y, dir = blockIdx.z;
    const int tid = threadIdx.x;
    __shared__ float gs[CL * 16];
    const float* gwd = gw + ((size_t)(dir * NB + b) * SEQ + chunk * CL) * 16;
    ((float4*)gs)[tid]       = ((const float4*)gwd)[tid];
    ((float4*)gs)[tid + 128] = ((const float4*)gwd)[tid + 128];
    __syncthreads();
    const ushort* vb = value + ((size_t)b * SEQ + chunk * CL) * 512 + dir * 256 + tid * 2;
    float c0[16] = {}, c1[16] = {};
    for (int i = 0; i < CL; ++i) {
        int row = dir ? (CL - 1 - i) : i;
        uint vv = *(const uint*)(vb + (size_t)row * 512);
        float v0 = bf2f((ushort)(vv & 0xffffu)), v1 = bf2f((ushort)(vv >> 16));
        float g[16];
        #pragma unroll
        for (int q = 0; q < 4; ++q)
            *(float4*)&g[q * 4] = *(const float4*)&gs[row * 16 + q * 4];
        #pragma unroll
        for (int s = 0; s < 16; ++s) {
            c0[s] = v0 + g[s] * (c0[s] - v0);
            c1[s] = v1 + g[s] * (c1[s] - v1);
        }
    }
    float* Lp = L + ((size_t)(dir * NB + b) * NC + chunk) * 4096 + tid * 2;
    #pragma unroll
    for (int s = 0; s < 16; ++s) {
        float2 t2; t2.x = c0[s]; t2.y = c1[s];
        *(float2*)(Lp + s * 256) = t2;
    }
    if (tid < 16) {
        float p = 1.f;
        for (int t = 0; t < CL; ++t) p *= gs[t * 16 + tid];
        P[((size_t)(dir * NB + b) * NC + chunk) * 16 + tid] = p;
    }
}

// ---------------- pass B: chunk-level recurrence (L -> entry states, in place) ----
__global__ __launch_bounds__(256) void chunk_scan(
    float* __restrict__ L, const float* __restrict__ P)
{
    const int bid = blockIdx.x;          // 128 = 2*4*16
    const int dir = bid >> 6, b = (bid >> 4) & 3, s = bid & 15;
    const int d = threadIdx.x;
    const size_t cb = (size_t)(dir * NB + b) * NC;
    float e = 0.f;
    #pragma unroll 4
    for (int i = 0; i < NC; ++i) {
        int k = dir ? (NC - 1 - i) : i;
        size_t off = (cb + k) * 4096 + s * 256 + d;
        float l = L[off];
        float pv = P[(cb + k) * 16 + s];
        L[off] = e;
        e = pv * e + l;
    }
}

// ---------------- pass C: re-run local scan with entry state, write in place ------
__global__ __launch_bounds__(128) void pass_c(
    ushort* __restrict__ value, const float* __restrict__ gw,
    const float* __restrict__ L, const float* __restrict__ A_f,
    const float* __restrict__ A_b)
{
    const int chunk = blockIdx.x, b = blockIdx.y, dir = blockIdx.z;
    const int tid = threadIdx.x;
    __shared__ float gs[CL * 16];
    const float* gwd = gw + ((size_t)(dir * NB + b) * SEQ + chunk * CL) * 16;
    ((float4*)gs)[tid]       = ((const float4*)gwd)[tid];
    ((float4*)gs)[tid + 128] = ((const float4*)gwd)[tid + 128];
    __syncthreads();
    ushort* vb = value + ((size_t)b * SEQ + chunk * CL) * 512 + dir * 256 + tid * 2;
    const float* Ad = dir ? A_b : A_f;
    const float* Lp = L + ((size_t)(dir * NB + b) * NC + chunk) * 4096 + tid * 2;
    float a0[16], a1[16], c0[16], c1[16];
    #pragma unroll
    for (int s = 0; s < 16; ++s) {
        float2 av = *(const float2*)(Ad + s * 256 + tid * 2);
        a0[s] = av.x; a1[s] = av.y;
        float2 cv = *(const float2*)(Lp + s * 256);
        c0[s] = cv.x; c1[s] = cv.y;
    }
    for (int i = 0; i < CL; ++i) {
        int row = dir ? (CL - 1 - i) : i;
        uint vv = *(const uint*)(vb + (size_t)row * 512);
        float v0 = bf2f((ushort)(vv & 0xffffu)), v1 = bf2f((ushort)(vv >> 16));
        float g[16];
        #pragma unroll
        for (int q = 0; q < 4; ++q)
            *(float4*)&g[q * 4] = *(const float4*)&gs[row * 16 + q * 4];
        float o0 = 0.f, o1 = 0.f;
        #pragma unroll
        for (int s = 0; s < 16; ++s) {
            c0[s] = v0 + g[s] * (c0[s] - v0);
            c1[s] = v1 + g[s] * (c1[s] - v1);
            o0 += a0[s] * (g[s] * c0[s]);
            o1 += a1[s] * (g[s] * c1[s]);
        }
        uint outv = (uint)f2bf(o0) | ((uint)f2bf(o1) << 16);
        *(uint*)(vb + (size_t)row * 512) = outv;
    }
}

// ---------------- out GEMM (K=512) with fused LayerNorm epilogue ----------------
__global__ __launch_bounds__(256) void gemm_out_ln(
    const ushort* __restrict__ A, const ushort* __restrict__ BT,
    const float* __restrict__ b_out, const float* __restrict__ ln_g,
    const float* __restrict__ ln_b, float* __restrict__ out)
{
    __shared__ ushort Al[64 * 40];
    __shared__ ushort Bl[256 * 40];
    __shared__ float red[2][4][64];
    const int tid = threadIdx.x;
    const int m0 = blockIdx.x * 64;
    const int w = tid >> 6, l = tid & 63, l15 = l & 15, lk = (l >> 4) * 8;
    f32x4 acc[4][4] = {};

    for (int kk = 0; kk < 512; kk += 32) {
        {
            int r = tid >> 2, c = tid & 3;
            *(uint4*)&Al[r * 40 + c * 8] = *(const uint4*)(A + (size_t)(m0 + r) * 512 + kk + c * 8);
        }
        #pragma unroll
        for (int i = 0; i < 4; ++i) {
            int idx = tid + i * 256; int r = idx >> 2, c = idx & 3;
            *(uint4*)&Bl[r * 40 + c * 8] = *(const uint4*)(BT + (size_t)r * 512 + kk + c * 8);
        }
        __syncthreads();
        bf16x8 af[4], bfr[4];
        #pragma unroll
        for (int m = 0; m < 4; ++m) af[m] = *(const bf16x8*)&Al[(m * 16 + l15) * 40 + lk];
        #pragma unroll
        for (int n = 0; n < 4; ++n) bfr[n] = *(const bf16x8*)&Bl[(w * 64 + n * 16 + l15) * 40 + lk];
        #pragma unroll
        for (int m = 0; m < 4; ++m)
            #pragma unroll
            for (int n = 0; n < 4; ++n)
                acc[m][n] = __builtin_amdgcn_mfma_f32_16x16x32_bf16(af[m], bfr[n], acc[m][n], 0, 0, 0);
        __syncthreads();
    }
    const int rbase = (l >> 4) * 4;
    float gg[4], bb[4];
    #pragma unroll
    for (int n = 0; n < 4; ++n) {
        int col = w * 64 + n * 16 + l15;
        float bv = b_out[col];
        gg[n] = ln_g[col]; bb[n] = ln_b[col];
        #pragma unroll
        for (int m = 0; m < 4; ++m)
            #pragma unroll
            for (int r = 0; r < 4; ++r)
                acc[m][n][r] += bv;
    }
    float s1[4][4], s2[4][4];
    #pragma unroll
    for (int m = 0; m < 4; ++m)
        #pragma unroll
        for (int r = 0; r < 4; ++r) {
            float a_ = 0.f, b_ = 0.f;
            #pragma unroll
            for (int n = 0; n < 4; ++n) {
                float v = acc[m][n][r];
                a_ += v; b_ += v * v;
            }
            s1[m][r] = a_; s2[m][r] = b_;
        }
    #pragma unroll
    for (int mask = 1; mask < 16; mask <<= 1)
        #pragma unroll
        for (int m = 0; m < 4; ++m)
            #pragma unroll
            for (int r = 0; r < 4; ++r) {
                s1[m][r] += __shfl_xor(s1[m][r], mask, 64);
                s2[m][r] += __shfl_xor(s2[m][r], mask, 64);
            }
    if (l15 == 0) {
        #pragma unroll
        for (int m = 0; m < 4; ++m)
            #pragma unroll
            for (int r = 0; r < 4; ++r) {
                int row = m * 16 + rbase + r;
                red[0][w][row] = s1[m][r];
                red[1][w][row] = s2[m][r];
            }
    }
    __syncthreads();
    #pragma unroll
    for (int m = 0; m < 4; ++m)
        #pragma unroll
        for (int r = 0; r < 4; ++r) {
            int row = m * 16 + rbase + r;
            float t1 = red[0][0][row] + red[0][1][row] + red[0][2][row] + red[0][3][row];
            float t2 = red[1][0][row] + red[1][1][row] + red[1][2][row] + red[1][3][row];
            float mu = t1 * (1.f / 256.f);
            float var = t2 * (1.f / 256.f) - mu * mu;
            float rs = rsqrtf(var + 1e-5f);
            #pragma unroll
            for (int n = 0; n < 4; ++n) {
                int col = w * 64 + n * 16 + l15;
                out[(size_t)(m0 + row) * 256 + col] = (acc[m][n][r] - mu) * rs * gg[n] + bb[n];
            }
        }
}

extern "C" void kernel_launch(void* const* d_in, const int* in_sizes, int n_in,
                              void* d_out, int out_size, void* d_ws, size_t ws_size,
                              hipStream_t stream)
{
    const float* x       = (const float*)d_in[0];
    const float* W_fproj = (const float*)d_in[1];
    const float* b_fproj = (const float*)d_in[2];
    const float* A_f     = (const float*)d_in[3];
    const float* W_fgate = (const float*)d_in[4];
    const float* b_fgate = (const float*)d_in[5];
    const float* W_bproj = (const float*)d_in[6];
    const float* b_bproj = (const float*)d_in[7];
    const float* A_b     = (const float*)d_in[8];
    const float* W_bgate = (const float*)d_in[9];
    const float* b_bgate = (const float*)d_in[10];
    const float* W_out   = (const float*)d_in[11];
    const float* b_out   = (const float*)d_in[12];
    const float* ln_g    = (const float*)d_in[13];
    const float* ln_b    = (const float*)d_in[14];

    char* ws = (char*)d_ws;
    ushort* value  = (ushort*)(ws + 0);             // 67108864 B  [row][512] (also holds combined)
    float*  gw     = (float*) (ws + 67108864);      //  8388608 B  [dir][b][t][16]
    float*  L      = (float*) (ws + 75497472);      // 33554432 B  [dir][b][chunk][s][256]
    float*  P      = (float*) (ws + 109051904);     //   524288 B
    ushort* BTv    = (ushort*)(ws + 109576192);     //   262144 B
    ushort* WoT    = (ushort*)(ws + 109838336);     //   262144 B
    ushort* WgT    = (ushort*)(ws + 110100480);     //    16384 B
    float*  bias_v = (float*) (ws + 110116864);     //     2048 B
    ushort* xb     = (ushort*)(ws + 110118912);     // 33554432 B

    prep_weights<<<1058, 256, 0, stream>>>(W_fproj, W_bproj, W_out, W_fgate, W_bgate,
                                           b_fproj, b_bproj, BTv, WoT, WgT, bias_v);
    xcvt<<<8192, 256, 0, stream>>>(x, xb);
    gemm_value<<<dim3(1024, 2), 256, 0, stream>>>(xb, BTv, bias_v, value);
    gate_mfma<<<dim3(1024, 2), 256, 0, stream>>>(value, WgT, b_fgate, b_bgate, gw);
    pass_a<<<dim3(NC, NB, 2), 128, 0, stream>>>(value, gw, L, P);
    chunk_scan<<<128, 256, 0, stream>>>(L, P);
    pass_c<<<dim3(NC, NB, 2), 128, 0, stream>>>(value, gw, L, A_f, A_b);
    gemm_out_ln<<<1024, 256, 0, stream>>>(value, WoT, b_out, ln_g, ln_b, (float*)d_out);
}